// Round 8
// baseline (227.525 us; speedup 1.0000x reference)
//
#include <hip/hip_runtime.h>

#define N_NODES 50000
#define N_EDGES 800000
#define NUM_GRAPHS 64

// Fixed-capacity CSR: deg ~ Poisson(16); P(deg>64) ~ 1e-18. cnt[n] counts
// accepted edges; slot base = n*CAP.
// r17: separate cnt[] (merged-line variant doubled scatter, r16).
// r19: counting-sort REVERTED. r20: 8-wide gather REVERTED.
// r21/r22: static scatter/gemm role-split fusion = ADDITIVE (~65us) — static
// partition never co-schedules; VGPR/LDS of gemm taxes scatter blocks.
// r23: DYNAMIC fusion — grid = exact standalone scatter shape (1024x256,
// G=4, cheap regs); after its slice each block pulls gemm tiles (r6 MT=48
// 2-col-tile geometry, 12.3KB K-split LDS) from an atomic ticket. Scatter
// keeps full parallelism; gemm fills scatter's imbalance slack.
#define CAPLOG 6
#define CAP    (1 << CAPLOG)
#define ZROW   N_NODES              // appended all-zero row in H1/H2/H3

__device__ __forceinline__ float bf_lo(unsigned u) { return __uint_as_float(u << 16); }
__device__ __forceinline__ float bf_hi(unsigned u) { return __uint_as_float(u & 0xffff0000u); }
__device__ __forceinline__ unsigned short f2bf(float f) {           // RNE
    unsigned u = __float_as_uint(f);
    return (unsigned short)((u + 0x7fffu + ((u >> 16) & 1u)) >> 16);
}

// 4-wide unrolled gather of 8 bf16 feats (r16; proven optimum r19/r20):
// one ushort4 index load + 4 independent uint4 gathers per step. Tail lanes
// redirect to the zero row (exact +0.0) so every step is full-width.
template<int S>
__device__ __forceinline__ void agg_row8(const unsigned short* __restrict__ Hc,
                                         const unsigned short* __restrict__ csr,
                                         int node, int m, float a[8]) {
    uint4 sv = *(const uint4*)(Hc + (size_t)node * S);              // self loop
    a[0] = bf_lo(sv.x); a[1] = bf_hi(sv.x); a[2] = bf_lo(sv.y); a[3] = bf_hi(sv.y);
    a[4] = bf_lo(sv.z); a[5] = bf_hi(sv.z); a[6] = bf_lo(sv.w); a[7] = bf_hi(sv.w);
    const int e0 = node << CAPLOG, e1 = e0 + m;
    for (int e = e0; e < e1; e += 4) {
        ushort4 ss = *(const ushort4*)&csr[e];     // 8B-aligned (e0 mult of 64)
        int s0 = ss.x;                             // e < e1 guaranteed
        int s1 = (e + 1 < e1) ? (int)ss.y : ZROW;
        int s2 = (e + 2 < e1) ? (int)ss.z : ZROW;
        int s3 = (e + 3 < e1) ? (int)ss.w : ZROW;
        uint4 v0 = *(const uint4*)(Hc + (size_t)s0 * S);
        uint4 v1 = *(const uint4*)(Hc + (size_t)s1 * S);
        uint4 v2 = *(const uint4*)(Hc + (size_t)s2 * S);
        uint4 v3 = *(const uint4*)(Hc + (size_t)s3 * S);
        a[0] += bf_lo(v0.x) + bf_lo(v1.x) + bf_lo(v2.x) + bf_lo(v3.x);
        a[1] += bf_hi(v0.x) + bf_hi(v1.x) + bf_hi(v2.x) + bf_hi(v3.x);
        a[2] += bf_lo(v0.y) + bf_lo(v1.y) + bf_lo(v2.y) + bf_lo(v3.y);
        a[3] += bf_hi(v0.y) + bf_hi(v1.y) + bf_hi(v2.y) + bf_hi(v3.y);
        a[4] += bf_lo(v0.z) + bf_lo(v1.z) + bf_lo(v2.z) + bf_lo(v3.z);
        a[5] += bf_hi(v0.z) + bf_hi(v1.z) + bf_hi(v2.z) + bf_hi(v3.z);
        a[6] += bf_lo(v0.w) + bf_lo(v1.w) + bf_lo(v2.w) + bf_lo(v3.w);
        a[7] += bf_hi(v0.w) + bf_hi(v1.w) + bf_hi(v2.w) + bf_hi(v3.w);
    }
}

// ---------------- FUSED: scatter (static) then gemm tiles (ticket) ----------
#define SC_NG    4
#define SC_BPG   256
#define SC_GRID  (SC_NG * SC_BPG)               // 1024 blocks = full grid
#define NPG      ((N_NODES + SC_NG - 1) / SC_NG)
#define GEMM_NBX ((N_NODES + 63) / 64)          // 782 node tiles of 64
#define GEMM_NB  (GEMM_NBX * 2)                 // 1564 (2 col-tiles of 48)
#define N_TICKETS (1 + GEMM_NB)                 // ticket 0 = graph bounds

__global__ __launch_bounds__(256) void k_fused(
        const int* __restrict__ ei, int* __restrict__ cnt,
        unsigned short* __restrict__ csr,
        const int* __restrict__ batch, int* __restrict__ start,
        const float* __restrict__ X, const float* __restrict__ W,
        float* __restrict__ Hraw, int* __restrict__ ticket) {
    __shared__ float ws[64 * 48];               // 12.3KB
    __shared__ int tkt;
    const int tid = threadIdx.x;

    // ---- phase 1: scatter slice — EXACT proven standalone shape ----
    {
        const int g  = blockIdx.x & (SC_NG - 1);
        const int b  = blockIdx.x / SC_NG;
        const int lo = g * NPG, hi = lo + NPG;
        const int* __restrict__ dst = ei + N_EDGES;
        for (int e = b * 256 + tid; e < N_EDGES; e += 256 * SC_BPG) {
            int d = dst[e];
            if (d >= lo && d < hi) {
                int old = atomicAdd(&cnt[d], 1);
                if (old < CAP) csr[(d << CAPLOG) + old] = (unsigned short)ei[e];
            }
        }
    }

    // ---- phase 2: pull gemm tiles (and the graph-bounds task) ----
    while (true) {
        if (tid == 0) tkt = atomicAdd(ticket, 1);
        __syncthreads();
        const int t = tkt;
        if (t >= N_TICKETS) break;              // uniform exit

        if (t == 0) {                           // graph bounds binary search
            if (tid <= NUM_GRAPHS) {
                int lo = 0, hi = N_NODES;
                while (lo < hi) {
                    int mid = (lo + hi) >> 1;
                    if (batch[mid] < tid) lo = mid + 1; else hi = mid;
                }
                start[tid] = lo;
            }
        } else {
            // gemm tile: K=128 in 2 halves, MT=48, FTH=12 x NTH=16, NT=4
            const int gidx = t - 1;
            const int bx = gidx % GEMM_NBX;
            const int by = gidx / GEMM_NBX;
            const int n0 = bx * 64;
            const int c0 = by * 48;
            const int ft = tid % 12;
            const int nt = tid / 12;            // 0..21; compute lanes nt<16
            const float* xp[4];
            float acc[4][4];
            #pragma unroll
            for (int i = 0; i < 4; ++i) {
                acc[i][0] = acc[i][1] = acc[i][2] = acc[i][3] = 0.f;
                int node = n0 + nt * 4 + i;
                int nc = node < N_NODES ? node : N_NODES - 1;
                xp[i] = X + (size_t)nc * 128;
            }
            for (int kh = 0; kh < 2; ++kh) {
                __syncthreads();                // protect ws before overwrite
                for (int i = tid; i < 64 * 48 / 4; i += 256) {
                    int k = i / 12, cv = i % 12;
                    *(float4*)&ws[k * 48 + cv * 4] =
                        *(const float4*)&W[(kh * 64 + k) * 96 + c0 + cv * 4];
                }
                __syncthreads();
                if (nt < 16) {
                    const int kb = kh * 64;
                    for (int k = 0; k < 64; k += 4) {
                        float4 w0 = *(const float4*)&ws[(k + 0) * 48 + ft * 4];
                        float4 w1 = *(const float4*)&ws[(k + 1) * 48 + ft * 4];
                        float4 w2 = *(const float4*)&ws[(k + 2) * 48 + ft * 4];
                        float4 w3 = *(const float4*)&ws[(k + 3) * 48 + ft * 4];
                        #pragma unroll
                        for (int i = 0; i < 4; ++i) {
                            float4 xv = *(const float4*)(xp[i] + kb + k);
                            acc[i][0] += xv.x * w0.x + xv.y * w1.x + xv.z * w2.x + xv.w * w3.x;
                            acc[i][1] += xv.x * w0.y + xv.y * w1.y + xv.z * w2.y + xv.w * w3.y;
                            acc[i][2] += xv.x * w0.z + xv.y * w1.z + xv.z * w2.z + xv.w * w3.z;
                            acc[i][3] += xv.x * w0.w + xv.y * w1.w + xv.z * w2.w + xv.w * w3.w;
                        }
                    }
                }
            }
            if (nt < 16) {
                #pragma unroll
                for (int i = 0; i < 4; ++i) {
                    int node = n0 + nt * 4 + i;
                    if (node < N_NODES)
                        *(float4*)&Hraw[(size_t)node * 96 + c0 + ft * 4] =
                            make_float4(acc[i][0], acc[i][1], acc[i][2], acc[i][3]);
                }
            }
        }
        __syncthreads();                        // tkt consumed + ws free
    }
}

// ---------------- scale pass: H1 = bf16(Hraw * dinv), + ZROW zeros ----------
// Numerically identical to the old fused epilogue (one fp32 mul + one RNE).
__global__ __launch_bounds__(256) void k_scale(
        const float* __restrict__ Hraw, const int* __restrict__ cnt,
        unsigned short* __restrict__ H1) {
    const int NQ = (N_NODES + 1) * 24;          // quads of 4 feats
    for (int q = blockIdx.x * 256 + threadIdx.x; q < NQ; q += gridDim.x * 256) {
        int n = q / 24, c = (q % 24) * 4;
        if (n == ZROW) {
            *(ushort4*)&H1[(size_t)n * 96 + c] = make_ushort4(0, 0, 0, 0);
            continue;
        }
        float s = rsqrtf((float)(cnt[n] + 1));
        float4 v = *(const float4*)&Hraw[(size_t)n * 96 + c];
        ushort4 o;
        o.x = f2bf(v.x * s); o.y = f2bf(v.y * s);
        o.z = f2bf(v.z * s); o.w = f2bf(v.w * s);
        *(ushort4*)&H1[(size_t)n * 96 + c] = o;
    }
}

// ---------------- fused agg(layer1) + gemm(layer2), 384thr/32 nodes ----------
__global__ __launch_bounds__(384) void k_agg12(
        const unsigned short* __restrict__ H1, const int* __restrict__ cnt,
        const unsigned short* __restrict__ csr, const float* __restrict__ b1,
        const float* __restrict__ W2, unsigned short* __restrict__ H2) {
    __shared__ float Ws[96 * 48];              // 18.4KB
    __shared__ float T[32][97];                // 12.4KB (+1 pad)
    __shared__ float dinvS[32];
    const int t = threadIdx.x;
    for (int i = t; i < 1152; i += 384)        // W2: 4608 floats = 1152 float4
        *(float4*)&Ws[i * 4] = *(const float4*)&W2[i * 4];

    if (blockIdx.x == 0 && t < 16) {           // H2 zero row (64 cols)
        ushort4 z = make_ushort4(0, 0, 0, 0);
        *(ushort4*)&H2[(size_t)ZROW * 64 + t * 4] = z;
    }

    // ---- phase A: aggregate 8 feats of one node (32 nodes x 12 chunks) ----
    const int n_l = t / 12, c = t % 12;
    const int node = blockIdx.x * 32 + n_l;
    if (node < N_NODES) {
        int deg = cnt[node];
        float d = rsqrtf((float)(deg + 1));
        if (c == 0) dinvS[n_l] = d;
        float a[8];
        agg_row8<96>(H1 + c * 8, csr, node, min(deg, CAP), a);
        const float4* bp = (const float4*)(b1 + c * 8);
        float4 b0 = bp[0], bb1 = bp[1];
        float* Tr = &T[n_l][c * 8];
        Tr[0] = fmaxf(a[0] * d + b0.x, 0.f);  Tr[1] = fmaxf(a[1] * d + b0.y, 0.f);
        Tr[2] = fmaxf(a[2] * d + b0.z, 0.f);  Tr[3] = fmaxf(a[3] * d + b0.w, 0.f);
        Tr[4] = fmaxf(a[4] * d + bb1.x, 0.f); Tr[5] = fmaxf(a[5] * d + bb1.y, 0.f);
        Tr[6] = fmaxf(a[6] * d + bb1.z, 0.f); Tr[7] = fmaxf(a[7] * d + bb1.w, 0.f);
    }
    __syncthreads();

    // ---- phase B: H2[n,:] = (T[n,:] @ W2) * dinv, bf16 (32 nodes x 12 f4) ---
    const int n2 = t / 12;
    const int f0 = (t % 12) * 4;
    const int gn = blockIdx.x * 32 + n2;
    if (gn < N_NODES) {
        float4 acc = make_float4(0.f, 0.f, 0.f, 0.f);
        for (int k = 0; k < 96; ++k) {
            float tv = T[n2][k];
            float4 wv = *(const float4*)&Ws[k * 48 + f0];
            acc.x += tv * wv.x; acc.y += tv * wv.y; acc.z += tv * wv.z; acc.w += tv * wv.w;
        }
        float s2 = dinvS[n2];
        ushort4 o;
        o.x = f2bf(acc.x * s2); o.y = f2bf(acc.y * s2);
        o.z = f2bf(acc.z * s2); o.w = f2bf(acc.w * s2);
        *(ushort4*)&H2[(size_t)gn * 64 + f0] = o;  // stride-64 rows (128B)
    }
}

// ---------------- fused agg(layer2) + gemm(layer3), 384thr/64 nodes ----------
__global__ __launch_bounds__(384) void k_agg23(
        const unsigned short* __restrict__ H2, const int* __restrict__ cnt,
        const unsigned short* __restrict__ csr, const float* __restrict__ b2,
        const float* __restrict__ W3, unsigned short* __restrict__ H3) {
    __shared__ float Ws[48 * 32];              // 6.1KB
    __shared__ float T[64][49];                // 12.5KB (+1 pad)
    __shared__ float dinvS[64];
    const int t = threadIdx.x;
    for (int i = t; i < 384; i += 384)         // W3: 1536 floats = 384 float4
        *(float4*)&Ws[i * 4] = *(const float4*)&W3[i * 4];

    if (blockIdx.x == 0 && t < 8) {            // H3 zero row (32 cols)
        ushort4 z = make_ushort4(0, 0, 0, 0);
        *(ushort4*)&H3[(size_t)ZROW * 32 + t * 4] = z;
    }

    // ---- phase A: aggregate 8 feats of one node (64 nodes x 6 chunks) ----
    const int n_l = t / 6, c = t % 6;
    const int node = blockIdx.x * 64 + n_l;
    if (node < N_NODES) {
        int deg = cnt[node];
        float d = rsqrtf((float)(deg + 1));
        if (c == 0) dinvS[n_l] = d;
        float a[8];
        agg_row8<64>(H2 + c * 8, csr, node, min(deg, CAP), a);
        const float4* bp = (const float4*)(b2 + c * 8);
        float4 b0 = bp[0], bb1 = bp[1];
        float* Tr = &T[n_l][c * 8];
        Tr[0] = fmaxf(a[0] * d + b0.x, 0.f);  Tr[1] = fmaxf(a[1] * d + b0.y, 0.f);
        Tr[2] = fmaxf(a[2] * d + b0.z, 0.f);  Tr[3] = fmaxf(a[3] * d + b0.w, 0.f);
        Tr[4] = fmaxf(a[4] * d + bb1.x, 0.f); Tr[5] = fmaxf(a[5] * d + bb1.y, 0.f);
        Tr[6] = fmaxf(a[6] * d + bb1.z, 0.f); Tr[7] = fmaxf(a[7] * d + bb1.w, 0.f);
    }
    __syncthreads();

    // ---- phase B: H3[n,:] = (T[n,:] @ W3) * dinv, bf16; 64x8 f4-groups ------
    for (int vid = t; vid < 512; vid += 384) {
        const int n2 = vid / 8;
        const int f0 = (vid % 8) * 4;
        const int gn = blockIdx.x * 64 + n2;
        if (gn < N_NODES) {
            float4 acc = make_float4(0.f, 0.f, 0.f, 0.f);
            for (int k = 0; k < 48; ++k) {
                float tv = T[n2][k];
                float4 wv = *(const float4*)&Ws[k * 32 + f0];
                acc.x += tv * wv.x; acc.y += tv * wv.y; acc.z += tv * wv.z; acc.w += tv * wv.w;
            }
            float s3 = dinvS[n2];
            ushort4 o;
            o.x = f2bf(acc.x * s3); o.y = f2bf(acc.y * s3);
            o.z = f2bf(acc.z * s3); o.w = f2bf(acc.w * s3);
            *(ushort4*)&H3[(size_t)gn * 32 + f0] = o;
        }
    }
}

// ---------------- fused agg(layer3) + mean-pool partials ---------------------
__global__ __launch_bounds__(256) void k_agg3p(
        const unsigned short* __restrict__ H3, const int* __restrict__ cnt,
        const unsigned short* __restrict__ csr, const float* __restrict__ b3,
        const int* __restrict__ batch, const int* __restrict__ start,
        float* __restrict__ gsum) {
    __shared__ float T[64][33];
    __shared__ float R[8][32];
    const int t = threadIdx.x;
    const int base = blockIdx.x * 64;

    // ---- phase A ----
    const int n_l = t / 4, c = t % 4;
    const int node = base + n_l;
    if (node < N_NODES) {
        int deg = cnt[node];
        float d = rsqrtf((float)(deg + 1));
        float a[8];
        agg_row8<32>(H3 + c * 8, csr, node, min(deg, CAP), a);
        const float4* bp = (const float4*)(b3 + c * 8);
        float4 b0 = bp[0], b1 = bp[1];
        float* Tr = &T[n_l][c * 8];
        Tr[0] = fmaxf(a[0] * d + b0.x, 0.f); Tr[1] = fmaxf(a[1] * d + b0.y, 0.f);
        Tr[2] = fmaxf(a[2] * d + b0.z, 0.f); Tr[3] = fmaxf(a[3] * d + b0.w, 0.f);
        Tr[4] = fmaxf(a[4] * d + b1.x, 0.f); Tr[5] = fmaxf(a[5] * d + b1.y, 0.f);
        Tr[6] = fmaxf(a[6] * d + b1.z, 0.f); Tr[7] = fmaxf(a[7] * d + b1.w, 0.f);
    }
    __syncthreads();

    // ---- phase B: per-segment reduction ----
    const int g_lo = batch[base < N_NODES ? base : N_NODES - 1];
    const int last = base + 63 < N_NODES ? base + 63 : N_NODES - 1;
    const int g_hi = batch[last];
    const int f = t & 31, k = t >> 5;          // 32 feats x 8 row-groups
    for (int g = g_lo; g <= g_hi; ++g) {
        int r_lo = start[g] - base;     if (r_lo < 0) r_lo = 0;
        int r_hi = start[g + 1] - base; if (r_hi > 64) r_hi = 64;
        float p = 0.f;
        for (int r = r_lo + k; r < r_hi; r += 8) p += T[r][f];
        R[k][f] = p;
        __syncthreads();
        if (k == 0) {
            float s = R[0][f] + R[1][f] + R[2][f] + R[3][f]
                    + R[4][f] + R[5][f] + R[6][f] + R[7][f];
            if (r_hi > r_lo) atomicAdd(&gsum[g * 32 + f], s);
        }
        __syncthreads();
    }
}

// ---------------- final: out = gsum / count ---------------------------------
__global__ void k_final(const float* __restrict__ gsum, const int* __restrict__ start,
                        float* __restrict__ out) {
    int t = blockIdx.x * blockDim.x + threadIdx.x;
    if (t < NUM_GRAPHS * 32) {
        int g = t >> 5;
        float c = (float)(start[g + 1] - start[g]);
        out[t] = gsum[t] / fmaxf(c, 1.0f);
    }
}

extern "C" void kernel_launch(void* const* d_in, const int* in_sizes, int n_in,
                              void* d_out, int out_size, void* d_ws, size_t ws_size,
                              hipStream_t stream) {
    const float* x     = (const float*)d_in[0];
    const int*   ei    = (const int*)d_in[1];
    const int*   batch = (const int*)d_in[2];
    const float* W1    = (const float*)d_in[3];
    const float* b1    = (const float*)d_in[4];
    const float* W2    = (const float*)d_in[5];
    const float* b2    = (const float*)d_in[6];
    const float* W3    = (const float*)d_in[7];
    const float* b3    = (const float*)d_in[8];
    float* out = (float*)d_out;

    char* ws = (char*)d_ws;
    size_t o = 0;
    auto alloc = [&](size_t bytes) {
        char* p = ws + o;
        o = (o + bytes + 255) & ~(size_t)255;
        return p;
    };
    // +1 row each: ZROW (all-zero row) for the predicated gather unroll
    unsigned short* H1 = (unsigned short*)alloc((size_t)(N_NODES + 1) * 96 * 2);
    unsigned short* H2 = (unsigned short*)alloc((size_t)(N_NODES + 1) * 64 * 2);
    unsigned short* H3 = (unsigned short*)alloc((size_t)(N_NODES + 1) * 32 * 2);
    float* H1raw  = (float*)alloc((size_t)N_NODES * 96 * 4);     // 19.2MB fp32
    int*   cnt    = (int*)alloc((size_t)N_NODES * 4);
    unsigned short* csr = (unsigned short*)alloc((size_t)N_NODES * CAP * 2);  // 6.4MB
    int*   start  = (int*)alloc((NUM_GRAPHS + 1) * 4);
    float* gsum   = (float*)alloc((size_t)NUM_GRAPHS * 32 * 4);
    int*   ticket = (int*)alloc(4);

    // zero counters, pool accumulators, and the gemm-tile ticket
    hipMemsetAsync(cnt, 0, (size_t)N_NODES * 4, stream);
    hipMemsetAsync(gsum, 0, (size_t)NUM_GRAPHS * 32 * 4, stream);
    hipMemsetAsync(ticket, 0, 4, stream);

    // FUSED: CSR build (static slices) -> gemm tiles (dynamic ticket)
    hipLaunchKernelGGL(k_fused, dim3(SC_GRID), dim3(256), 0, stream,
                       ei, cnt, csr, batch, start, x, W1, H1raw, ticket);
    // scale pass: H1 = bf16(H1raw * dinv)  (bit-identical to old epilogue)
    hipLaunchKernelGGL(k_scale, dim3(2048), dim3(256), 0, stream, H1raw, cnt, H1);
    // agg1 + gemm2 fused (32 nodes/block, 384 threads)
    hipLaunchKernelGGL(k_agg12, dim3((N_NODES + 31) / 32), dim3(384), 0, stream,
                       H1, cnt, csr, b1, W2, H2);
    // agg2 + gemm3 fused (64 nodes/block, 384 threads)
    hipLaunchKernelGGL(k_agg23, dim3((N_NODES + 63) / 64), dim3(384), 0, stream,
                       H2, cnt, csr, b2, W3, H3);
    // agg3 + pool partials fused (64 nodes/block, 256 threads)
    hipLaunchKernelGGL(k_agg3p, dim3((N_NODES + 63) / 64), dim3(256), 0, stream,
                       H3, cnt, csr, b3, batch, start, gsum);
    // final division
    hipLaunchKernelGGL(k_final, dim3((NUM_GRAPHS * 32 + 255) / 256), dim3(256), 0, stream,
                       gsum, start, out);
}

// Round 9
// 208.862 us; speedup vs baseline: 1.0894x; 1.0894x over previous
//
#include <hip/hip_runtime.h>

#define N_NODES 50000
#define N_EDGES 800000
#define NUM_GRAPHS 64

// Fixed-capacity CSR: deg ~ Poisson(16); P(deg>64) ~ 1e-18. cnt[n] counts
// accepted edges; slot base = n*CAP.
// r17: separate cnt[] (merged-line doubled scatter, r16). r19: counting-sort
// REVERTED. r20: 8-wide gather REVERTED. r23: dynamic ticket fusion REVERTED
// (+17us: slices finish together -> no slack; 25% lanes idle in gemm).
// r24 = r21 (best measured, 210.5us) + scatter LANE PARITY: SC_BPG 256->341
// so scatter role = 1364 blocks x 192 thr = 262k lanes, matching the proven
// standalone scatter's lane count (r21 had 196k -> scatter stretched ~57us).
// Gemm role (MT=48, K-split 12.3KB LDS, 2 col-tiles) unchanged from r21.
#define CAPLOG 6
#define CAP    (1 << CAPLOG)
#define ZROW   N_NODES              // appended all-zero row in H1/H2/H3

__device__ __forceinline__ float bf_lo(unsigned u) { return __uint_as_float(u << 16); }
__device__ __forceinline__ float bf_hi(unsigned u) { return __uint_as_float(u & 0xffff0000u); }
__device__ __forceinline__ unsigned short f2bf(float f) {           // RNE
    unsigned u = __float_as_uint(f);
    return (unsigned short)((u + 0x7fffu + ((u >> 16) & 1u)) >> 16);
}

// 4-wide unrolled gather of 8 bf16 feats (r16; proven optimum r19/r20):
// one ushort4 index load + 4 independent uint4 gathers per step. Tail lanes
// redirect to the zero row (exact +0.0) so every step is full-width.
template<int S>
__device__ __forceinline__ void agg_row8(const unsigned short* __restrict__ Hc,
                                         const unsigned short* __restrict__ csr,
                                         int node, int m, float a[8]) {
    uint4 sv = *(const uint4*)(Hc + (size_t)node * S);              // self loop
    a[0] = bf_lo(sv.x); a[1] = bf_hi(sv.x); a[2] = bf_lo(sv.y); a[3] = bf_hi(sv.y);
    a[4] = bf_lo(sv.z); a[5] = bf_hi(sv.z); a[6] = bf_lo(sv.w); a[7] = bf_hi(sv.w);
    const int e0 = node << CAPLOG, e1 = e0 + m;
    for (int e = e0; e < e1; e += 4) {
        ushort4 ss = *(const ushort4*)&csr[e];     // 8B-aligned (e0 mult of 64)
        int s0 = ss.x;                             // e < e1 guaranteed
        int s1 = (e + 1 < e1) ? (int)ss.y : ZROW;
        int s2 = (e + 2 < e1) ? (int)ss.z : ZROW;
        int s3 = (e + 3 < e1) ? (int)ss.w : ZROW;
        uint4 v0 = *(const uint4*)(Hc + (size_t)s0 * S);
        uint4 v1 = *(const uint4*)(Hc + (size_t)s1 * S);
        uint4 v2 = *(const uint4*)(Hc + (size_t)s2 * S);
        uint4 v3 = *(const uint4*)(Hc + (size_t)s3 * S);
        a[0] += bf_lo(v0.x) + bf_lo(v1.x) + bf_lo(v2.x) + bf_lo(v3.x);
        a[1] += bf_hi(v0.x) + bf_hi(v1.x) + bf_hi(v2.x) + bf_hi(v3.x);
        a[2] += bf_lo(v0.y) + bf_lo(v1.y) + bf_lo(v2.y) + bf_lo(v3.y);
        a[3] += bf_hi(v0.y) + bf_hi(v1.y) + bf_hi(v2.y) + bf_hi(v3.y);
        a[4] += bf_lo(v0.z) + bf_lo(v1.z) + bf_lo(v2.z) + bf_lo(v3.z);
        a[5] += bf_hi(v0.z) + bf_hi(v1.z) + bf_hi(v2.z) + bf_hi(v3.z);
        a[6] += bf_lo(v0.w) + bf_lo(v1.w) + bf_lo(v2.w) + bf_lo(v3.w);
        a[7] += bf_hi(v0.w) + bf_hi(v1.w) + bf_hi(v2.w) + bf_hi(v3.w);
    }
}

// ---------------- FUSED: group-local CSR scatter ∥ GEMM1 (fp32 out) ----------
// Role interleave: bid<2728: even=scatter(bid/2), odd=gemm(bid/2);
// bid==2728: graph-bounds; bid>2728: gemm(1364 + bid-2729).
#define SC_NG    4
#define SC_BPG   341
#define SC_GRID  (SC_NG * SC_BPG)               // 1364 scatter blocks (262k lanes)
#define NPG      ((N_NODES + SC_NG - 1) / SC_NG)
#define GEMM_NBX ((N_NODES + 63) / 64)          // 782
#define GEMM_NB  (GEMM_NBX * 2)                 // 1564 (2 col-tiles of 48)
#define FUSE_GRID (2 * SC_GRID + 1 + (GEMM_NB - SC_GRID))   // 2929

__global__ __launch_bounds__(192) void k_scatgemm(
        const int* __restrict__ ei, int* __restrict__ cnt,
        unsigned short* __restrict__ csr,
        const int* __restrict__ batch, int* __restrict__ start,
        const float* __restrict__ X, const float* __restrict__ W,
        float* __restrict__ Hraw) {
    const int bid = blockIdx.x;
    const int tid = threadIdx.x;

    int role, idx;
    if (bid < 2 * SC_GRID) { role = bid & 1; idx = bid >> 1; }
    else if (bid == 2 * SC_GRID) {              // ---- graph bounds ----
        if (tid <= NUM_GRAPHS) {
            int lo = 0, hi = N_NODES;
            while (lo < hi) {
                int mid = (lo + hi) >> 1;
                if (batch[mid] < tid) lo = mid + 1; else hi = mid;
            }
            start[tid] = lo;
        }
        return;
    }
    else { role = 1; idx = SC_GRID + (bid - 2 * SC_GRID - 1); }

    if (role == 0) {                            // ---- scatter part ----
        const int g  = idx & (SC_NG - 1);
        const int b  = idx / SC_NG;
        const int lo = g * NPG, hi = lo + NPG;
        const int* __restrict__ dst = ei + N_EDGES;
        for (int e = b * 192 + tid; e < N_EDGES; e += 192 * SC_BPG) {
            int d = dst[e];
            if (d >= lo && d < hi) {
                int old = atomicAdd(&cnt[d], 1);
                if (old < CAP) csr[(d << CAPLOG) + old] = (unsigned short)ei[e];
            }
        }
        return;
    }

    // ---- gemm part: K=128 in 2 halves of 64 (12.3KB LDS), MT=48, NT=4 ----
    const int bx = idx % GEMM_NBX;
    const int by = idx / GEMM_NBX;
    const int n0 = bx * 64;
    const int c0 = by * 48;
    __shared__ float ws[64 * 48];               // 12.3KB

    const int ft = tid % 12;
    const int nt = tid / 12;
    const float* xp[4];
    #pragma unroll
    for (int i = 0; i < 4; ++i) {
        int node = n0 + nt * 4 + i;
        int nc = node < N_NODES ? node : N_NODES - 1;   // clamp; store guarded
        xp[i] = X + (size_t)nc * 128;
    }
    float acc[4][4];
    #pragma unroll
    for (int i = 0; i < 4; ++i) { acc[i][0] = acc[i][1] = acc[i][2] = acc[i][3] = 0.f; }

    for (int kh = 0; kh < 2; ++kh) {
        __syncthreads();                        // protect ws before overwrite
        for (int i = tid; i < 64 * 48 / 4; i += 192) {
            int k = i / 12, cv = i % 12;
            *(float4*)&ws[k * 48 + cv * 4] =
                *(const float4*)&W[(kh * 64 + k) * 96 + c0 + cv * 4];
        }
        __syncthreads();
        const int kb = kh * 64;
        for (int k = 0; k < 64; k += 4) {
            float4 w0 = *(const float4*)&ws[(k + 0) * 48 + ft * 4];
            float4 w1 = *(const float4*)&ws[(k + 1) * 48 + ft * 4];
            float4 w2 = *(const float4*)&ws[(k + 2) * 48 + ft * 4];
            float4 w3 = *(const float4*)&ws[(k + 3) * 48 + ft * 4];
            #pragma unroll
            for (int i = 0; i < 4; ++i) {
                float4 xv = *(const float4*)(xp[i] + kb + k);
                acc[i][0] += xv.x * w0.x + xv.y * w1.x + xv.z * w2.x + xv.w * w3.x;
                acc[i][1] += xv.x * w0.y + xv.y * w1.y + xv.z * w2.y + xv.w * w3.y;
                acc[i][2] += xv.x * w0.z + xv.y * w1.z + xv.z * w2.z + xv.w * w3.z;
                acc[i][3] += xv.x * w0.w + xv.y * w1.w + xv.z * w2.w + xv.w * w3.w;
            }
        }
    }
    #pragma unroll
    for (int i = 0; i < 4; ++i) {
        int node = n0 + nt * 4 + i;
        if (node < N_NODES)
            *(float4*)&Hraw[(size_t)node * 96 + c0 + ft * 4] =
                make_float4(acc[i][0], acc[i][1], acc[i][2], acc[i][3]);
    }
}

// ---------------- scale pass: H1 = bf16(Hraw * dinv), + ZROW zeros ----------
// Numerically identical to the old fused epilogue (one fp32 mul + one RNE).
__global__ __launch_bounds__(256) void k_scale(
        const float* __restrict__ Hraw, const int* __restrict__ cnt,
        unsigned short* __restrict__ H1) {
    const int NQ = (N_NODES + 1) * 24;          // quads of 4 feats
    for (int q = blockIdx.x * 256 + threadIdx.x; q < NQ; q += gridDim.x * 256) {
        int n = q / 24, c = (q % 24) * 4;
        if (n == ZROW) {
            *(ushort4*)&H1[(size_t)n * 96 + c] = make_ushort4(0, 0, 0, 0);
            continue;
        }
        float s = rsqrtf((float)(cnt[n] + 1));
        float4 v = *(const float4*)&Hraw[(size_t)n * 96 + c];
        ushort4 o;
        o.x = f2bf(v.x * s); o.y = f2bf(v.y * s);
        o.z = f2bf(v.z * s); o.w = f2bf(v.w * s);
        *(ushort4*)&H1[(size_t)n * 96 + c] = o;
    }
}

// ---------------- fused agg(layer1) + gemm(layer2), 384thr/32 nodes ----------
__global__ __launch_bounds__(384) void k_agg12(
        const unsigned short* __restrict__ H1, const int* __restrict__ cnt,
        const unsigned short* __restrict__ csr, const float* __restrict__ b1,
        const float* __restrict__ W2, unsigned short* __restrict__ H2) {
    __shared__ float Ws[96 * 48];              // 18.4KB
    __shared__ float T[32][97];                // 12.4KB (+1 pad)
    __shared__ float dinvS[32];
    const int t = threadIdx.x;
    for (int i = t; i < 1152; i += 384)        // W2: 4608 floats = 1152 float4
        *(float4*)&Ws[i * 4] = *(const float4*)&W2[i * 4];

    if (blockIdx.x == 0 && t < 16) {           // H2 zero row (64 cols)
        ushort4 z = make_ushort4(0, 0, 0, 0);
        *(ushort4*)&H2[(size_t)ZROW * 64 + t * 4] = z;
    }

    // ---- phase A: aggregate 8 feats of one node (32 nodes x 12 chunks) ----
    const int n_l = t / 12, c = t % 12;
    const int node = blockIdx.x * 32 + n_l;
    if (node < N_NODES) {
        int deg = cnt[node];
        float d = rsqrtf((float)(deg + 1));
        if (c == 0) dinvS[n_l] = d;
        float a[8];
        agg_row8<96>(H1 + c * 8, csr, node, min(deg, CAP), a);
        const float4* bp = (const float4*)(b1 + c * 8);
        float4 b0 = bp[0], bb1 = bp[1];
        float* Tr = &T[n_l][c * 8];
        Tr[0] = fmaxf(a[0] * d + b0.x, 0.f);  Tr[1] = fmaxf(a[1] * d + b0.y, 0.f);
        Tr[2] = fmaxf(a[2] * d + b0.z, 0.f);  Tr[3] = fmaxf(a[3] * d + b0.w, 0.f);
        Tr[4] = fmaxf(a[4] * d + bb1.x, 0.f); Tr[5] = fmaxf(a[5] * d + bb1.y, 0.f);
        Tr[6] = fmaxf(a[6] * d + bb1.z, 0.f); Tr[7] = fmaxf(a[7] * d + bb1.w, 0.f);
    }
    __syncthreads();

    // ---- phase B: H2[n,:] = (T[n,:] @ W2) * dinv, bf16 (32 nodes x 12 f4) ---
    const int n2 = t / 12;
    const int f0 = (t % 12) * 4;
    const int gn = blockIdx.x * 32 + n2;
    if (gn < N_NODES) {
        float4 acc = make_float4(0.f, 0.f, 0.f, 0.f);
        for (int k = 0; k < 96; ++k) {
            float tv = T[n2][k];
            float4 wv = *(const float4*)&Ws[k * 48 + f0];
            acc.x += tv * wv.x; acc.y += tv * wv.y; acc.z += tv * wv.z; acc.w += tv * wv.w;
        }
        float s2 = dinvS[n2];
        ushort4 o;
        o.x = f2bf(acc.x * s2); o.y = f2bf(acc.y * s2);
        o.z = f2bf(acc.z * s2); o.w = f2bf(acc.w * s2);
        *(ushort4*)&H2[(size_t)gn * 64 + f0] = o;  // stride-64 rows (128B)
    }
}

// ---------------- fused agg(layer2) + gemm(layer3), 384thr/64 nodes ----------
__global__ __launch_bounds__(384) void k_agg23(
        const unsigned short* __restrict__ H2, const int* __restrict__ cnt,
        const unsigned short* __restrict__ csr, const float* __restrict__ b2,
        const float* __restrict__ W3, unsigned short* __restrict__ H3) {
    __shared__ float Ws[48 * 32];              // 6.1KB
    __shared__ float T[64][49];                // 12.5KB (+1 pad)
    __shared__ float dinvS[64];
    const int t = threadIdx.x;
    for (int i = t; i < 384; i += 384)         // W3: 1536 floats = 384 float4
        *(float4*)&Ws[i * 4] = *(const float4*)&W3[i * 4];

    if (blockIdx.x == 0 && t < 8) {            // H3 zero row (32 cols)
        ushort4 z = make_ushort4(0, 0, 0, 0);
        *(ushort4*)&H3[(size_t)ZROW * 32 + t * 4] = z;
    }

    // ---- phase A: aggregate 8 feats of one node (64 nodes x 6 chunks) ----
    const int n_l = t / 6, c = t % 6;
    const int node = blockIdx.x * 64 + n_l;
    if (node < N_NODES) {
        int deg = cnt[node];
        float d = rsqrtf((float)(deg + 1));
        if (c == 0) dinvS[n_l] = d;
        float a[8];
        agg_row8<64>(H2 + c * 8, csr, node, min(deg, CAP), a);
        const float4* bp = (const float4*)(b2 + c * 8);
        float4 b0 = bp[0], bb1 = bp[1];
        float* Tr = &T[n_l][c * 8];
        Tr[0] = fmaxf(a[0] * d + b0.x, 0.f);  Tr[1] = fmaxf(a[1] * d + b0.y, 0.f);
        Tr[2] = fmaxf(a[2] * d + b0.z, 0.f);  Tr[3] = fmaxf(a[3] * d + b0.w, 0.f);
        Tr[4] = fmaxf(a[4] * d + bb1.x, 0.f); Tr[5] = fmaxf(a[5] * d + bb1.y, 0.f);
        Tr[6] = fmaxf(a[6] * d + bb1.z, 0.f); Tr[7] = fmaxf(a[7] * d + bb1.w, 0.f);
    }
    __syncthreads();

    // ---- phase B: H3[n,:] = (T[n,:] @ W3) * dinv, bf16; 64x8 f4-groups ------
    for (int vid = t; vid < 512; vid += 384) {
        const int n2 = vid / 8;
        const int f0 = (vid % 8) * 4;
        const int gn = blockIdx.x * 64 + n2;
        if (gn < N_NODES) {
            float4 acc = make_float4(0.f, 0.f, 0.f, 0.f);
            for (int k = 0; k < 48; ++k) {
                float tv = T[n2][k];
                float4 wv = *(const float4*)&Ws[k * 32 + f0];
                acc.x += tv * wv.x; acc.y += tv * wv.y; acc.z += tv * wv.z; acc.w += tv * wv.w;
            }
            float s3 = dinvS[n2];
            ushort4 o;
            o.x = f2bf(acc.x * s3); o.y = f2bf(acc.y * s3);
            o.z = f2bf(acc.z * s3); o.w = f2bf(acc.w * s3);
            *(ushort4*)&H3[(size_t)gn * 32 + f0] = o;
        }
    }
}

// ---------------- fused agg(layer3) + mean-pool partials ---------------------
__global__ __launch_bounds__(256) void k_agg3p(
        const unsigned short* __restrict__ H3, const int* __restrict__ cnt,
        const unsigned short* __restrict__ csr, const float* __restrict__ b3,
        const int* __restrict__ batch, const int* __restrict__ start,
        float* __restrict__ gsum) {
    __shared__ float T[64][33];
    __shared__ float R[8][32];
    const int t = threadIdx.x;
    const int base = blockIdx.x * 64;

    // ---- phase A ----
    const int n_l = t / 4, c = t % 4;
    const int node = base + n_l;
    if (node < N_NODES) {
        int deg = cnt[node];
        float d = rsqrtf((float)(deg + 1));
        float a[8];
        agg_row8<32>(H3 + c * 8, csr, node, min(deg, CAP), a);
        const float4* bp = (const float4*)(b3 + c * 8);
        float4 b0 = bp[0], b1 = bp[1];
        float* Tr = &T[n_l][c * 8];
        Tr[0] = fmaxf(a[0] * d + b0.x, 0.f); Tr[1] = fmaxf(a[1] * d + b0.y, 0.f);
        Tr[2] = fmaxf(a[2] * d + b0.z, 0.f); Tr[3] = fmaxf(a[3] * d + b0.w, 0.f);
        Tr[4] = fmaxf(a[4] * d + b1.x, 0.f); Tr[5] = fmaxf(a[5] * d + b1.y, 0.f);
        Tr[6] = fmaxf(a[6] * d + b1.z, 0.f); Tr[7] = fmaxf(a[7] * d + b1.w, 0.f);
    }
    __syncthreads();

    // ---- phase B: per-segment reduction ----
    const int g_lo = batch[base < N_NODES ? base : N_NODES - 1];
    const int last = base + 63 < N_NODES ? base + 63 : N_NODES - 1;
    const int g_hi = batch[last];
    const int f = t & 31, k = t >> 5;          // 32 feats x 8 row-groups
    for (int g = g_lo; g <= g_hi; ++g) {
        int r_lo = start[g] - base;     if (r_lo < 0) r_lo = 0;
        int r_hi = start[g + 1] - base; if (r_hi > 64) r_hi = 64;
        float p = 0.f;
        for (int r = r_lo + k; r < r_hi; r += 8) p += T[r][f];
        R[k][f] = p;
        __syncthreads();
        if (k == 0) {
            float s = R[0][f] + R[1][f] + R[2][f] + R[3][f]
                    + R[4][f] + R[5][f] + R[6][f] + R[7][f];
            if (r_hi > r_lo) atomicAdd(&gsum[g * 32 + f], s);
        }
        __syncthreads();
    }
}

// ---------------- final: out = gsum / count ---------------------------------
__global__ void k_final(const float* __restrict__ gsum, const int* __restrict__ start,
                        float* __restrict__ out) {
    int t = blockIdx.x * blockDim.x + threadIdx.x;
    if (t < NUM_GRAPHS * 32) {
        int g = t >> 5;
        float c = (float)(start[g + 1] - start[g]);
        out[t] = gsum[t] / fmaxf(c, 1.0f);
    }
}

extern "C" void kernel_launch(void* const* d_in, const int* in_sizes, int n_in,
                              void* d_out, int out_size, void* d_ws, size_t ws_size,
                              hipStream_t stream) {
    const float* x     = (const float*)d_in[0];
    const int*   ei    = (const int*)d_in[1];
    const int*   batch = (const int*)d_in[2];
    const float* W1    = (const float*)d_in[3];
    const float* b1    = (const float*)d_in[4];
    const float* W2    = (const float*)d_in[5];
    const float* b2    = (const float*)d_in[6];
    const float* W3    = (const float*)d_in[7];
    const float* b3    = (const float*)d_in[8];
    float* out = (float*)d_out;

    char* ws = (char*)d_ws;
    size_t o = 0;
    auto alloc = [&](size_t bytes) {
        char* p = ws + o;
        o = (o + bytes + 255) & ~(size_t)255;
        return p;
    };
    // +1 row each: ZROW (all-zero row) for the predicated gather unroll
    unsigned short* H1 = (unsigned short*)alloc((size_t)(N_NODES + 1) * 96 * 2);
    unsigned short* H2 = (unsigned short*)alloc((size_t)(N_NODES + 1) * 64 * 2);
    unsigned short* H3 = (unsigned short*)alloc((size_t)(N_NODES + 1) * 32 * 2);
    float* H1raw  = (float*)alloc((size_t)N_NODES * 96 * 4);     // 19.2MB fp32
    int*   cnt    = (int*)alloc((size_t)N_NODES * 4);
    unsigned short* csr = (unsigned short*)alloc((size_t)N_NODES * CAP * 2);  // 6.4MB
    int*   start  = (int*)alloc((NUM_GRAPHS + 1) * 4);
    float* gsum   = (float*)alloc((size_t)NUM_GRAPHS * 32 * 4);

    // zero the edge counters and pool accumulators (stream-ordered DMA)
    hipMemsetAsync(cnt, 0, (size_t)N_NODES * 4, stream);
    hipMemsetAsync(gsum, 0, (size_t)NUM_GRAPHS * 32 * 4, stream);

    // FUSED: CSR build ∥ layer-1 GEMM (fp32 raw out), roles interleaved
    hipLaunchKernelGGL(k_scatgemm, dim3(FUSE_GRID), dim3(192), 0, stream,
                       ei, cnt, csr, batch, start, x, W1, H1raw);
    // scale pass: H1 = bf16(H1raw * dinv)  (bit-identical to old epilogue)
    hipLaunchKernelGGL(k_scale, dim3(2048), dim3(256), 0, stream, H1raw, cnt, H1);
    // agg1 + gemm2 fused (32 nodes/block, 384 threads)
    hipLaunchKernelGGL(k_agg12, dim3((N_NODES + 31) / 32), dim3(384), 0, stream,
                       H1, cnt, csr, b1, W2, H2);
    // agg2 + gemm3 fused (64 nodes/block, 384 threads)
    hipLaunchKernelGGL(k_agg23, dim3((N_NODES + 63) / 64), dim3(384), 0, stream,
                       H2, cnt, csr, b2, W3, H3);
    // agg3 + pool partials fused (64 nodes/block, 256 threads)
    hipLaunchKernelGGL(k_agg3p, dim3((N_NODES + 63) / 64), dim3(256), 0, stream,
                       H3, cnt, csr, b3, batch, start, gsum);
    // final division
    hipLaunchKernelGGL(k_final, dim3((NUM_GRAPHS * 32 + 255) / 256), dim3(256), 0, stream,
                       gsum, start, out);
}

// Round 10
// 200.727 us; speedup vs baseline: 1.1335x; 1.0405x over previous
//
#include <hip/hip_runtime.h>

#define N_NODES 50000
#define N_EDGES 800000
#define NUM_GRAPHS 64

// Fixed-capacity CSR: deg ~ Poisson(16); P(deg>64) ~ 1e-18. cnt[n] counts
// accepted edges; slot base = n*CAP.
// r17: separate cnt[]. r19: counting-sort REVERTED. r20: 8-wide REVERTED.
// r23: dynamic ticket REVERTED. r24: fused scatter∥gemm with lane parity
// (SC_BPG=341, 262k scatter lanes) = best measured (208.9us).
// r25: k_scale DELETED — gemm writes UNSCALED bf16 H1; agg12 applies the
// src-side dinv at gather time (loads cnt[s] from L2-resident table,
// rsqrt on the fly; VALU headroom is free under the MSHR-bound gather).
// Same # of bf16 roundings -> absmax unchanged. cnt has +1 entry so
// cnt[ZROW]=0 -> ds=1 x zero row = exact 0.
#define CAPLOG 6
#define CAP    (1 << CAPLOG)
#define ZROW   N_NODES              // appended all-zero row in H1/H2/H3

__device__ __forceinline__ float bf_lo(unsigned u) { return __uint_as_float(u << 16); }
__device__ __forceinline__ float bf_hi(unsigned u) { return __uint_as_float(u & 0xffff0000u); }
__device__ __forceinline__ unsigned short f2bf(float f) {           // RNE
    unsigned u = __float_as_uint(f);
    return (unsigned short)((u + 0x7fffu + ((u >> 16) & 1u)) >> 16);
}

// 4-wide unrolled gather of 8 bf16 feats (r16; proven optimum r19/r20):
// one ushort4 index load + 4 independent uint4 gathers per step. Tail lanes
// redirect to the zero row (exact +0.0) so every step is full-width.
template<int S>
__device__ __forceinline__ void agg_row8(const unsigned short* __restrict__ Hc,
                                         const unsigned short* __restrict__ csr,
                                         int node, int m, float a[8]) {
    uint4 sv = *(const uint4*)(Hc + (size_t)node * S);              // self loop
    a[0] = bf_lo(sv.x); a[1] = bf_hi(sv.x); a[2] = bf_lo(sv.y); a[3] = bf_hi(sv.y);
    a[4] = bf_lo(sv.z); a[5] = bf_hi(sv.z); a[6] = bf_lo(sv.w); a[7] = bf_hi(sv.w);
    const int e0 = node << CAPLOG, e1 = e0 + m;
    for (int e = e0; e < e1; e += 4) {
        ushort4 ss = *(const ushort4*)&csr[e];     // 8B-aligned (e0 mult of 64)
        int s0 = ss.x;                             // e < e1 guaranteed
        int s1 = (e + 1 < e1) ? (int)ss.y : ZROW;
        int s2 = (e + 2 < e1) ? (int)ss.z : ZROW;
        int s3 = (e + 3 < e1) ? (int)ss.w : ZROW;
        uint4 v0 = *(const uint4*)(Hc + (size_t)s0 * S);
        uint4 v1 = *(const uint4*)(Hc + (size_t)s1 * S);
        uint4 v2 = *(const uint4*)(Hc + (size_t)s2 * S);
        uint4 v3 = *(const uint4*)(Hc + (size_t)s3 * S);
        a[0] += bf_lo(v0.x) + bf_lo(v1.x) + bf_lo(v2.x) + bf_lo(v3.x);
        a[1] += bf_hi(v0.x) + bf_hi(v1.x) + bf_hi(v2.x) + bf_hi(v3.x);
        a[2] += bf_lo(v0.y) + bf_lo(v1.y) + bf_lo(v2.y) + bf_lo(v3.y);
        a[3] += bf_hi(v0.y) + bf_hi(v1.y) + bf_hi(v2.y) + bf_hi(v3.y);
        a[4] += bf_lo(v0.z) + bf_lo(v1.z) + bf_lo(v2.z) + bf_lo(v3.z);
        a[5] += bf_hi(v0.z) + bf_hi(v1.z) + bf_hi(v2.z) + bf_hi(v3.z);
        a[6] += bf_lo(v0.w) + bf_lo(v1.w) + bf_lo(v2.w) + bf_lo(v3.w);
        a[7] += bf_hi(v0.w) + bf_hi(v1.w) + bf_hi(v2.w) + bf_hi(v3.w);
    }
}

// r25 variant for agg12: H1 rows are UNSCALED — multiply each gathered row
// by dinv[s] = rsqrt(cnt[s]+1) at accumulation time (fma, same op count).
__device__ __forceinline__ void agg_row8_dinv(
        const unsigned short* __restrict__ Hc, const unsigned short* __restrict__ csr,
        const int* __restrict__ cnt, int node, int m, float d_self, float a[8]) {
    uint4 sv = *(const uint4*)(Hc + (size_t)node * 96);             // self loop
    a[0] = bf_lo(sv.x) * d_self; a[1] = bf_hi(sv.x) * d_self;
    a[2] = bf_lo(sv.y) * d_self; a[3] = bf_hi(sv.y) * d_self;
    a[4] = bf_lo(sv.z) * d_self; a[5] = bf_hi(sv.z) * d_self;
    a[6] = bf_lo(sv.w) * d_self; a[7] = bf_hi(sv.w) * d_self;
    const int e0 = node << CAPLOG, e1 = e0 + m;
    for (int e = e0; e < e1; e += 4) {
        ushort4 ss = *(const ushort4*)&csr[e];
        int s0 = ss.x;
        int s1 = (e + 1 < e1) ? (int)ss.y : ZROW;
        int s2 = (e + 2 < e1) ? (int)ss.z : ZROW;
        int s3 = (e + 3 < e1) ? (int)ss.w : ZROW;
        uint4 v0 = *(const uint4*)(Hc + (size_t)s0 * 96);
        uint4 v1 = *(const uint4*)(Hc + (size_t)s1 * 96);
        uint4 v2 = *(const uint4*)(Hc + (size_t)s2 * 96);
        uint4 v3 = *(const uint4*)(Hc + (size_t)s3 * 96);
        float d0 = rsqrtf((float)(cnt[s0] + 1));    // cnt[ZROW]=0 -> ds=1
        float d1 = rsqrtf((float)(cnt[s1] + 1));
        float d2 = rsqrtf((float)(cnt[s2] + 1));
        float d3 = rsqrtf((float)(cnt[s3] + 1));
        a[0] += bf_lo(v0.x) * d0 + bf_lo(v1.x) * d1 + bf_lo(v2.x) * d2 + bf_lo(v3.x) * d3;
        a[1] += bf_hi(v0.x) * d0 + bf_hi(v1.x) * d1 + bf_hi(v2.x) * d2 + bf_hi(v3.x) * d3;
        a[2] += bf_lo(v0.y) * d0 + bf_lo(v1.y) * d1 + bf_lo(v2.y) * d2 + bf_lo(v3.y) * d3;
        a[3] += bf_hi(v0.y) * d0 + bf_hi(v1.y) * d1 + bf_hi(v2.y) * d2 + bf_hi(v3.y) * d3;
        a[4] += bf_lo(v0.z) * d0 + bf_lo(v1.z) * d1 + bf_lo(v2.z) * d2 + bf_lo(v3.z) * d3;
        a[5] += bf_hi(v0.z) * d0 + bf_hi(v1.z) * d1 + bf_hi(v2.z) * d2 + bf_hi(v3.z) * d3;
        a[6] += bf_lo(v0.w) * d0 + bf_lo(v1.w) * d1 + bf_lo(v2.w) * d2 + bf_lo(v3.w) * d3;
        a[7] += bf_hi(v0.w) * d0 + bf_hi(v1.w) * d1 + bf_hi(v2.w) * d2 + bf_hi(v3.w) * d3;
    }
}

// ---------------- FUSED: group-local CSR scatter ∥ GEMM1 (bf16 out) ----------
// Role interleave: bid<2728: even=scatter(bid/2), odd=gemm(bid/2);
// bid==2728: graph-bounds + H1 ZROW; bid>2728: gemm(1364 + bid-2729).
#define SC_NG    4
#define SC_BPG   341
#define SC_GRID  (SC_NG * SC_BPG)               // 1364 scatter blocks (262k lanes)
#define NPG      ((N_NODES + SC_NG - 1) / SC_NG)
#define GEMM_NBX ((N_NODES + 63) / 64)          // 782
#define GEMM_NB  (GEMM_NBX * 2)                 // 1564 (2 col-tiles of 48)
#define FUSE_GRID (2 * SC_GRID + 1 + (GEMM_NB - SC_GRID))   // 2929

__global__ __launch_bounds__(192) void k_scatgemm(
        const int* __restrict__ ei, int* __restrict__ cnt,
        unsigned short* __restrict__ csr,
        const int* __restrict__ batch, int* __restrict__ start,
        const float* __restrict__ X, const float* __restrict__ W,
        unsigned short* __restrict__ H1) {
    const int bid = blockIdx.x;
    const int tid = threadIdx.x;

    int role, idx;
    if (bid < 2 * SC_GRID) { role = bid & 1; idx = bid >> 1; }
    else if (bid == 2 * SC_GRID) {              // ---- graph bounds + ZROW ----
        if (tid <= NUM_GRAPHS) {
            int lo = 0, hi = N_NODES;
            while (lo < hi) {
                int mid = (lo + hi) >> 1;
                if (batch[mid] < tid) lo = mid + 1; else hi = mid;
            }
            start[tid] = lo;
        }
        if (tid >= 128 && tid < 152) {          // H1 zero row: 24 ushort4
            ushort4 z = make_ushort4(0, 0, 0, 0);
            *(ushort4*)&H1[(size_t)ZROW * 96 + (tid - 128) * 4] = z;
        }
        return;
    }
    else { role = 1; idx = SC_GRID + (bid - 2 * SC_GRID - 1); }

    if (role == 0) {                            // ---- scatter part ----
        const int g  = idx & (SC_NG - 1);
        const int b  = idx / SC_NG;
        const int lo = g * NPG, hi = lo + NPG;
        const int* __restrict__ dst = ei + N_EDGES;
        for (int e = b * 192 + tid; e < N_EDGES; e += 192 * SC_BPG) {
            int d = dst[e];
            if (d >= lo && d < hi) {
                int old = atomicAdd(&cnt[d], 1);
                if (old < CAP) csr[(d << CAPLOG) + old] = (unsigned short)ei[e];
            }
        }
        return;
    }

    // ---- gemm part: K=128 in 2 halves of 64 (12.3KB LDS), MT=48, NT=4 ----
    const int bx = idx % GEMM_NBX;
    const int by = idx / GEMM_NBX;
    const int n0 = bx * 64;
    const int c0 = by * 48;
    __shared__ float ws[64 * 48];               // 12.3KB

    const int ft = tid % 12;
    const int nt = tid / 12;
    const float* xp[4];
    #pragma unroll
    for (int i = 0; i < 4; ++i) {
        int node = n0 + nt * 4 + i;
        int nc = node < N_NODES ? node : N_NODES - 1;   // clamp; store guarded
        xp[i] = X + (size_t)nc * 128;
    }
    float acc[4][4];
    #pragma unroll
    for (int i = 0; i < 4; ++i) { acc[i][0] = acc[i][1] = acc[i][2] = acc[i][3] = 0.f; }

    for (int kh = 0; kh < 2; ++kh) {
        __syncthreads();                        // protect ws before overwrite
        for (int i = tid; i < 64 * 48 / 4; i += 192) {
            int k = i / 12, cv = i % 12;
            *(float4*)&ws[k * 48 + cv * 4] =
                *(const float4*)&W[(kh * 64 + k) * 96 + c0 + cv * 4];
        }
        __syncthreads();
        const int kb = kh * 64;
        for (int k = 0; k < 64; k += 4) {
            float4 w0 = *(const float4*)&ws[(k + 0) * 48 + ft * 4];
            float4 w1 = *(const float4*)&ws[(k + 1) * 48 + ft * 4];
            float4 w2 = *(const float4*)&ws[(k + 2) * 48 + ft * 4];
            float4 w3 = *(const float4*)&ws[(k + 3) * 48 + ft * 4];
            #pragma unroll
            for (int i = 0; i < 4; ++i) {
                float4 xv = *(const float4*)(xp[i] + kb + k);
                acc[i][0] += xv.x * w0.x + xv.y * w1.x + xv.z * w2.x + xv.w * w3.x;
                acc[i][1] += xv.x * w0.y + xv.y * w1.y + xv.z * w2.y + xv.w * w3.y;
                acc[i][2] += xv.x * w0.z + xv.y * w1.z + xv.z * w2.z + xv.w * w3.z;
                acc[i][3] += xv.x * w0.w + xv.y * w1.w + xv.z * w2.w + xv.w * w3.w;
            }
        }
    }
    #pragma unroll
    for (int i = 0; i < 4; ++i) {
        int node = n0 + nt * 4 + i;
        if (node < N_NODES) {
            ushort4 o;                          // UNSCALED bf16 (r25)
            o.x = f2bf(acc[i][0]); o.y = f2bf(acc[i][1]);
            o.z = f2bf(acc[i][2]); o.w = f2bf(acc[i][3]);
            *(ushort4*)&H1[(size_t)node * 96 + c0 + ft * 4] = o;
        }
    }
}

// ---------------- fused agg(layer1) + gemm(layer2), 384thr/32 nodes ----------
// r25: H1 unscaled; src dinv applied at gather via cnt[] (L2-resident).
__global__ __launch_bounds__(384) void k_agg12(
        const unsigned short* __restrict__ H1, const int* __restrict__ cnt,
        const unsigned short* __restrict__ csr, const float* __restrict__ b1,
        const float* __restrict__ W2, unsigned short* __restrict__ H2) {
    __shared__ float Ws[96 * 48];              // 18.4KB
    __shared__ float T[32][97];                // 12.4KB (+1 pad)
    __shared__ float dinvS[32];
    const int t = threadIdx.x;
    for (int i = t; i < 1152; i += 384)        // W2: 4608 floats = 1152 float4
        *(float4*)&Ws[i * 4] = *(const float4*)&W2[i * 4];

    if (blockIdx.x == 0 && t < 16) {           // H2 zero row (64 cols)
        ushort4 z = make_ushort4(0, 0, 0, 0);
        *(ushort4*)&H2[(size_t)ZROW * 64 + t * 4] = z;
    }

    // ---- phase A: aggregate 8 feats of one node (32 nodes x 12 chunks) ----
    const int n_l = t / 12, c = t % 12;
    const int node = blockIdx.x * 32 + n_l;
    if (node < N_NODES) {
        int deg = cnt[node];
        float d = rsqrtf((float)(deg + 1));
        if (c == 0) dinvS[n_l] = d;
        float a[8];
        agg_row8_dinv(H1 + c * 8, csr, cnt, node, min(deg, CAP), d, a);
        const float4* bp = (const float4*)(b1 + c * 8);
        float4 b0 = bp[0], bb1 = bp[1];
        float* Tr = &T[n_l][c * 8];
        Tr[0] = fmaxf(a[0] * d + b0.x, 0.f);  Tr[1] = fmaxf(a[1] * d + b0.y, 0.f);
        Tr[2] = fmaxf(a[2] * d + b0.z, 0.f);  Tr[3] = fmaxf(a[3] * d + b0.w, 0.f);
        Tr[4] = fmaxf(a[4] * d + bb1.x, 0.f); Tr[5] = fmaxf(a[5] * d + bb1.y, 0.f);
        Tr[6] = fmaxf(a[6] * d + bb1.z, 0.f); Tr[7] = fmaxf(a[7] * d + bb1.w, 0.f);
    }
    __syncthreads();

    // ---- phase B: H2[n,:] = (T[n,:] @ W2) * dinv, bf16 (32 nodes x 12 f4) ---
    const int n2 = t / 12;
    const int f0 = (t % 12) * 4;
    const int gn = blockIdx.x * 32 + n2;
    if (gn < N_NODES) {
        float4 acc = make_float4(0.f, 0.f, 0.f, 0.f);
        for (int k = 0; k < 96; ++k) {
            float tv = T[n2][k];
            float4 wv = *(const float4*)&Ws[k * 48 + f0];
            acc.x += tv * wv.x; acc.y += tv * wv.y; acc.z += tv * wv.z; acc.w += tv * wv.w;
        }
        float s2 = dinvS[n2];
        ushort4 o;
        o.x = f2bf(acc.x * s2); o.y = f2bf(acc.y * s2);
        o.z = f2bf(acc.z * s2); o.w = f2bf(acc.w * s2);
        *(ushort4*)&H2[(size_t)gn * 64 + f0] = o;  // stride-64 rows (128B)
    }
}

// ---------------- fused agg(layer2) + gemm(layer3), 384thr/64 nodes ----------
__global__ __launch_bounds__(384) void k_agg23(
        const unsigned short* __restrict__ H2, const int* __restrict__ cnt,
        const unsigned short* __restrict__ csr, const float* __restrict__ b2,
        const float* __restrict__ W3, unsigned short* __restrict__ H3) {
    __shared__ float Ws[48 * 32];              // 6.1KB
    __shared__ float T[64][49];                // 12.5KB (+1 pad)
    __shared__ float dinvS[64];
    const int t = threadIdx.x;
    for (int i = t; i < 384; i += 384)         // W3: 1536 floats = 384 float4
        *(float4*)&Ws[i * 4] = *(const float4*)&W3[i * 4];

    if (blockIdx.x == 0 && t < 8) {            // H3 zero row (32 cols)
        ushort4 z = make_ushort4(0, 0, 0, 0);
        *(ushort4*)&H3[(size_t)ZROW * 32 + t * 4] = z;
    }

    // ---- phase A: aggregate 8 feats of one node (64 nodes x 6 chunks) ----
    const int n_l = t / 6, c = t % 6;
    const int node = blockIdx.x * 64 + n_l;
    if (node < N_NODES) {
        int deg = cnt[node];
        float d = rsqrtf((float)(deg + 1));
        if (c == 0) dinvS[n_l] = d;
        float a[8];
        agg_row8<64>(H2 + c * 8, csr, node, min(deg, CAP), a);
        const float4* bp = (const float4*)(b2 + c * 8);
        float4 b0 = bp[0], bb1 = bp[1];
        float* Tr = &T[n_l][c * 8];
        Tr[0] = fmaxf(a[0] * d + b0.x, 0.f);  Tr[1] = fmaxf(a[1] * d + b0.y, 0.f);
        Tr[2] = fmaxf(a[2] * d + b0.z, 0.f);  Tr[3] = fmaxf(a[3] * d + b0.w, 0.f);
        Tr[4] = fmaxf(a[4] * d + bb1.x, 0.f); Tr[5] = fmaxf(a[5] * d + bb1.y, 0.f);
        Tr[6] = fmaxf(a[6] * d + bb1.z, 0.f); Tr[7] = fmaxf(a[7] * d + bb1.w, 0.f);
    }
    __syncthreads();

    // ---- phase B: H3[n,:] = (T[n,:] @ W3) * dinv, bf16; 64x8 f4-groups ------
    for (int vid = t; vid < 512; vid += 384) {
        const int n2 = vid / 8;
        const int f0 = (vid % 8) * 4;
        const int gn = blockIdx.x * 64 + n2;
        if (gn < N_NODES) {
            float4 acc = make_float4(0.f, 0.f, 0.f, 0.f);
            for (int k = 0; k < 48; ++k) {
                float tv = T[n2][k];
                float4 wv = *(const float4*)&Ws[k * 32 + f0];
                acc.x += tv * wv.x; acc.y += tv * wv.y; acc.z += tv * wv.z; acc.w += tv * wv.w;
            }
            float s3 = dinvS[n2];
            ushort4 o;
            o.x = f2bf(acc.x * s3); o.y = f2bf(acc.y * s3);
            o.z = f2bf(acc.z * s3); o.w = f2bf(acc.w * s3);
            *(ushort4*)&H3[(size_t)gn * 32 + f0] = o;
        }
    }
}

// ---------------- fused agg(layer3) + mean-pool partials ---------------------
__global__ __launch_bounds__(256) void k_agg3p(
        const unsigned short* __restrict__ H3, const int* __restrict__ cnt,
        const unsigned short* __restrict__ csr, const float* __restrict__ b3,
        const int* __restrict__ batch, const int* __restrict__ start,
        float* __restrict__ gsum) {
    __shared__ float T[64][33];
    __shared__ float R[8][32];
    const int t = threadIdx.x;
    const int base = blockIdx.x * 64;

    // ---- phase A ----
    const int n_l = t / 4, c = t % 4;
    const int node = base + n_l;
    if (node < N_NODES) {
        int deg = cnt[node];
        float d = rsqrtf((float)(deg + 1));
        float a[8];
        agg_row8<32>(H3 + c * 8, csr, node, min(deg, CAP), a);
        const float4* bp = (const float4*)(b3 + c * 8);
        float4 b0 = bp[0], b1 = bp[1];
        float* Tr = &T[n_l][c * 8];
        Tr[0] = fmaxf(a[0] * d + b0.x, 0.f); Tr[1] = fmaxf(a[1] * d + b0.y, 0.f);
        Tr[2] = fmaxf(a[2] * d + b0.z, 0.f); Tr[3] = fmaxf(a[3] * d + b0.w, 0.f);
        Tr[4] = fmaxf(a[4] * d + b1.x, 0.f); Tr[5] = fmaxf(a[5] * d + b1.y, 0.f);
        Tr[6] = fmaxf(a[6] * d + b1.z, 0.f); Tr[7] = fmaxf(a[7] * d + b1.w, 0.f);
    }
    __syncthreads();

    // ---- phase B: per-segment reduction ----
    const int g_lo = batch[base < N_NODES ? base : N_NODES - 1];
    const int last = base + 63 < N_NODES ? base + 63 : N_NODES - 1;
    const int g_hi = batch[last];
    const int f = t & 31, k = t >> 5;          // 32 feats x 8 row-groups
    for (int g = g_lo; g <= g_hi; ++g) {
        int r_lo = start[g] - base;     if (r_lo < 0) r_lo = 0;
        int r_hi = start[g + 1] - base; if (r_hi > 64) r_hi = 64;
        float p = 0.f;
        for (int r = r_lo + k; r < r_hi; r += 8) p += T[r][f];
        R[k][f] = p;
        __syncthreads();
        if (k == 0) {
            float s = R[0][f] + R[1][f] + R[2][f] + R[3][f]
                    + R[4][f] + R[5][f] + R[6][f] + R[7][f];
            if (r_hi > r_lo) atomicAdd(&gsum[g * 32 + f], s);
        }
        __syncthreads();
    }
}

// ---------------- final: out = gsum / count ---------------------------------
__global__ void k_final(const float* __restrict__ gsum, const int* __restrict__ start,
                        float* __restrict__ out) {
    int t = blockIdx.x * blockDim.x + threadIdx.x;
    if (t < NUM_GRAPHS * 32) {
        int g = t >> 5;
        float c = (float)(start[g + 1] - start[g]);
        out[t] = gsum[t] / fmaxf(c, 1.0f);
    }
}

extern "C" void kernel_launch(void* const* d_in, const int* in_sizes, int n_in,
                              void* d_out, int out_size, void* d_ws, size_t ws_size,
                              hipStream_t stream) {
    const float* x     = (const float*)d_in[0];
    const int*   ei    = (const int*)d_in[1];
    const int*   batch = (const int*)d_in[2];
    const float* W1    = (const float*)d_in[3];
    const float* b1    = (const float*)d_in[4];
    const float* W2    = (const float*)d_in[5];
    const float* b2    = (const float*)d_in[6];
    const float* W3    = (const float*)d_in[7];
    const float* b3    = (const float*)d_in[8];
    float* out = (float*)d_out;

    char* ws = (char*)d_ws;
    size_t o = 0;
    auto alloc = [&](size_t bytes) {
        char* p = ws + o;
        o = (o + bytes + 255) & ~(size_t)255;
        return p;
    };
    // +1 row each: ZROW (all-zero row) for the predicated gather unroll
    unsigned short* H1 = (unsigned short*)alloc((size_t)(N_NODES + 1) * 96 * 2);
    unsigned short* H2 = (unsigned short*)alloc((size_t)(N_NODES + 1) * 64 * 2);
    unsigned short* H3 = (unsigned short*)alloc((size_t)(N_NODES + 1) * 32 * 2);
    int*   cnt    = (int*)alloc((size_t)(N_NODES + 1) * 4);      // +1: cnt[ZROW]=0
    unsigned short* csr = (unsigned short*)alloc((size_t)N_NODES * CAP * 2);  // 6.4MB
    int*   start  = (int*)alloc((NUM_GRAPHS + 1) * 4);
    float* gsum   = (float*)alloc((size_t)NUM_GRAPHS * 32 * 4);

    // zero the edge counters (incl. ZROW entry) and pool accumulators
    hipMemsetAsync(cnt, 0, (size_t)(N_NODES + 1) * 4, stream);
    hipMemsetAsync(gsum, 0, (size_t)NUM_GRAPHS * 32 * 4, stream);

    // FUSED: CSR build ∥ layer-1 GEMM (unscaled bf16 out), roles interleaved
    hipLaunchKernelGGL(k_scatgemm, dim3(FUSE_GRID), dim3(192), 0, stream,
                       ei, cnt, csr, batch, start, x, W1, H1);
    // agg1 + gemm2 fused (32 nodes/block, 384 threads; src dinv at gather)
    hipLaunchKernelGGL(k_agg12, dim3((N_NODES + 31) / 32), dim3(384), 0, stream,
                       H1, cnt, csr, b1, W2, H2);
    // agg2 + gemm3 fused (64 nodes/block, 384 threads)
    hipLaunchKernelGGL(k_agg23, dim3((N_NODES + 63) / 64), dim3(384), 0, stream,
                       H2, cnt, csr, b2, W3, H3);
    // agg3 + pool partials fused (64 nodes/block, 256 threads)
    hipLaunchKernelGGL(k_agg3p, dim3((N_NODES + 63) / 64), dim3(256), 0, stream,
                       H3, cnt, csr, b3, batch, start, gsum);
    // final division
    hipLaunchKernelGGL(k_final, dim3((NUM_GRAPHS * 32 + 255) / 256), dim3(256), 0, stream,
                       gsum, start, out);
}